// Round 11
// baseline (78.000 us; speedup 1.0000x reference)
//
#include <hip/hip_runtime.h>

typedef __attribute__((ext_vector_type(8))) _Float16 f16x8;
typedef __attribute__((ext_vector_type(4))) float f32x4;

#define HSTR 264   // fp16 per A/C row (528B): 16B-aligned, staggered banks

// ---- prep: weights -> fp16, fragment-contiguous (lane-major) into d_ws ----
// One wave-fragment (64 lanes x 16B) contiguous -> in-kernel weight loads are
// single fully-coalesced 1KB dwordx4 transactions.
__global__ __launch_bounds__(256) void prep_kernel(
    const float* __restrict__ gW0, const float* __restrict__ gW1,
    _Float16* __restrict__ W0c, _Float16* __restrict__ W1c)
{
  const int t = blockIdx.x * 256 + threadIdx.x;  // 0..65535
  {
    const int c = t >> 7, k = t & 127;           // c in [0,512), k in [0,128)
    const int dst = ((k >> 5) * 32 + (c >> 4)) * 512 +
                    (((k >> 3) & 3) * 16 + (c & 15)) * 8 + (k & 7);
    const int src = (k + ((c >= 256) ? 128 : 0)) * 256 + (c & 255);
    W0c[dst] = (_Float16)gW0[src];
  }
  {
    const int n = t >> 8, k = t & 255;           // n in [0,256), k in [0,256)
    const int dst = ((k >> 5) * 16 + (n >> 4)) * 512 +
                    (((k >> 3) & 3) * 16 + (n & 15)) * 8 + (k & 7);
    W1c[dst] = (_Float16)gW1[k * 256 + n];
  }
}

// ---- main: per-batch pair MLP + pooled sum, fp16, 4 waves, AGPR weights ----
// Rounds 3-10: the allocator remats/spills weight fragments in the VGPR class
// no matter what (VGPR_Count pinned ~64-132). Fix: park W1 fragments in the
// AGPR side of gfx950's unified file (zero pressure there) via an opaque
// "+a" pin, and issue phase-3 MFMAs as inline asm with B in "a" constraint
// (ISA: MFMA A/B may come from AGPR). 4 waves x 64 cols: bw = 128 AGPR,
// u-build redundancy halved vs r10 (4 waves share A instead of 8).
// Explicit s_nops cover VALU<->MFMA hazards the compiler can't see in asm.
__global__ __launch_bounds__(256, 2) void pair_kernel(
    const float* __restrict__ state,
    const _Float16* __restrict__ W0c, const float* __restrict__ gb0,
    const _Float16* __restrict__ W1c, const float* __restrict__ gb1,
    float* __restrict__ pooled)
{
  const int b   = blockIdx.x;
  const int tid = threadIdx.x;
  const int w   = tid >> 6;   // wave 0..3
  const int l   = tid & 63;
  const int lr  = l & 15;
  const int lg  = l >> 4;

  __shared__ _Float16 A_lds[16 * HSTR];
  __shared__ _Float16 C_lds[16 * HSTR];

  const float* stb = state + (size_t)b * 2048;

  // ---------------- Phase 2: [A|C] = state[16x128] @ W0 (fp16 MFMA) ----------------
  f16x8 sfrag[4];
  #pragma unroll
  for (int kk = 0; kk < 4; ++kk) {
    const float* sp = stb + lr * 128 + kk * 32 + lg * 8;
    f32x4 s0 = *(const f32x4*)sp;
    f32x4 s1 = *(const f32x4*)(sp + 4);
    f16x8 f;
    f[0] = (_Float16)s0[0]; f[1] = (_Float16)s0[1];
    f[2] = (_Float16)s0[2]; f[3] = (_Float16)s0[3];
    f[4] = (_Float16)s1[0]; f[5] = (_Float16)s1[1];
    f[6] = (_Float16)s1[2]; f[7] = (_Float16)s1[3];
    sfrag[kk] = f;
  }

  const f32x4 z4 = {0.f, 0.f, 0.f, 0.f};
  f32x4 acc2[8];
  #pragma unroll
  for (int nt = 0; nt < 8; ++nt) acc2[nt] = z4;

  // wave w owns [A|C] cols [128w, 128w+128)
  #pragma unroll
  for (int nt = 0; nt < 8; ++nt) {
    #pragma unroll
    for (int kk = 0; kk < 4; ++kk) {
      f16x8 bf = *(const f16x8*)(W0c + (size_t)((kk * 32 + 8 * w + nt) * 512 + l * 8));
      acc2[nt] = __builtin_amdgcn_mfma_f32_16x16x32_f16(sfrag[kk], bf, acc2[nt], 0, 0, 0);
    }
  }

  // store phase-2 results as fp16 (C/D layout: col=lr, row=lg*4+r); fold gb0
  #pragma unroll
  for (int nt = 0; nt < 8; ++nt) {
    const int col = 128 * w + 16 * nt + lr;
    #pragma unroll
    for (int r = 0; r < 4; ++r) {
      const int row = lg * 4 + r;
      const float v = acc2[nt][r];
      if (col < 256) A_lds[row * HSTR + col]       = (_Float16)(v + gb0[col]);
      else           C_lds[row * HSTR + col - 256] = (_Float16)v;
    }
  }
  __syncthreads();

  // C rows -> fp16 registers: lane (lr,lg) holds C[lr][kk*32+lg*8 .. +8]
  f16x8 creg[8];
  #pragma unroll
  for (int kk = 0; kk < 8; ++kk)
    creg[kk] = *(const f16x8*)&C_lds[lr * HSTR + kk * 32 + lg * 8];

  // W1 fragments: wave w owns N-cols [64w, 64w+64) -> 4nt x 8kk frags.
  // Pin each into an AGPR tuple: opaque def, zero VGPR-class pressure.
  f16x8 bw[4][8];
  #pragma unroll
  for (int nt = 0; nt < 4; ++nt) {
    #pragma unroll
    for (int kk = 0; kk < 8; ++kk) {
      bw[nt][kk] = *(const f16x8*)(W1c + (size_t)((kk * 16 + 4 * w + nt) * 512 + l * 8));
      asm volatile("" : "+a"(bw[nt][kk]));   // park in AGPR, un-rematerializable
    }
  }

  float gb1v[4];
  #pragma unroll
  for (int nt = 0; nt < 4; ++nt) gb1v[nt] = gb1[64 * w + 16 * nt + lr];

  const f16x8 zh = {(_Float16)0, (_Float16)0, (_Float16)0, (_Float16)0,
                    (_Float16)0, (_Float16)0, (_Float16)0, (_Float16)0};

  // ---------------- Phase 3: 16 i-tiles; u = relu(A_i + C_j) in fp16 ----------------
  float pp[4] = {0.f, 0.f, 0.f, 0.f};
  #pragma unroll 1
  for (int i = 0; i < 16; ++i) {
    f32x4 a0 = z4, a1 = z4, a2 = z4, a3 = z4;
    #pragma unroll
    for (int kk = 0; kk < 8; ++kk) {
      f16x8 av = *(const f16x8*)&A_lds[i * HSTR + kk * 32 + lg * 8];  // bcast read
      f16x8 u = __builtin_elementwise_max(av + creg[kk], zh);
      // s_nop covers VALU-write(u/acc) -> MFMA-read hazard (asm is opaque to
      // the hazard recognizer); later MFMAs are naturally spaced.
      asm volatile("s_nop 3\n\tv_mfma_f32_16x16x32_f16 %0, %1, %2, %0"
                   : "+v"(a0) : "v"(u), "a"(bw[0][kk]));
      asm volatile("v_mfma_f32_16x16x32_f16 %0, %1, %2, %0"
                   : "+v"(a1) : "v"(u), "a"(bw[1][kk]));
      asm volatile("v_mfma_f32_16x16x32_f16 %0, %1, %2, %0"
                   : "+v"(a2) : "v"(u), "a"(bw[2][kk]));
      asm volatile("v_mfma_f32_16x16x32_f16 %0, %1, %2, %0"
                   : "+v"(a3) : "v"(u), "a"(bw[3][kk]));
    }
    // MFMA-write -> VALU-read spacing before the epilogue touches acc
    asm volatile("s_nop 7\n\ts_nop 7");

    #pragma unroll
    for (int r = 0; r < 4; ++r) {
      const int row = lg * 4 + r;       // = j
      const float v0 = fmaxf(a0[r] + gb1v[0], 0.f);
      const float v1 = fmaxf(a1[r] + gb1v[1], 0.f);
      const float v2 = fmaxf(a2[r] + gb1v[2], 0.f);
      const float v3 = fmaxf(a3[r] + gb1v[3], 0.f);
      pp[0] += (row == i) ? 0.f : v0;   // mask the (i,i) filler pair
      pp[1] += (row == i) ? 0.f : v1;
      pp[2] += (row == i) ? 0.f : v2;
      pp[3] += (row == i) ? 0.f : v3;
    }
  }

  // reduce the 4 lane-groups (disjoint j subsets, same col), write pooled
  #pragma unroll
  for (int nt = 0; nt < 4; ++nt) {
    float v = pp[nt];
    v += __shfl_xor(v, 16);
    v += __shfl_xor(v, 32);
    if (lg == 0) pooled[(size_t)b * 256 + 64 * w + 16 * nt + lr] = v;
  }
}

// ---- f-MLP: 256 blocks x 4 batches (all CUs busy; weights L2-resident) ----
__global__ __launch_bounds__(256) void fmlp_kernel(
    const float* __restrict__ pooled,
    const float* __restrict__ fW0, const float* __restrict__ fb0,
    const float* __restrict__ fW1, const float* __restrict__ fb1,
    float* __restrict__ out)
{
  const int tid = threadIdx.x;
  const size_t b0 = (size_t)blockIdx.x * 4;
  __shared__ float pl[4][256];
  __shared__ float h1[4][256];

  #pragma unroll
  for (int q = 0; q < 4; ++q)
    pl[q][tid] = pooled[(b0 + q) * 256 + tid];
  __syncthreads();

  float acc[4] = {0.f, 0.f, 0.f, 0.f};
  #pragma unroll 8
  for (int k = 0; k < 256; ++k) {
    const float wv = fW0[(size_t)k * 256 + tid];
    #pragma unroll
    for (int q = 0; q < 4; ++q) acc[q] = fmaf(pl[q][k], wv, acc[q]);
  }
  #pragma unroll
  for (int q = 0; q < 4; ++q) h1[q][tid] = fmaxf(acc[q] + fb0[tid], 0.f);
  __syncthreads();

  float acc2[4] = {0.f, 0.f, 0.f, 0.f};
  #pragma unroll 8
  for (int k = 0; k < 256; ++k) {
    const float wv = fW1[(size_t)k * 256 + tid];
    #pragma unroll
    for (int q = 0; q < 4; ++q) acc2[q] = fmaf(h1[q][k], wv, acc2[q]);
  }
  #pragma unroll
  for (int q = 0; q < 4; ++q)
    out[(b0 + q) * 256 + tid] = fmaxf(acc2[q] + fb1[tid], 0.f);
}

extern "C" void kernel_launch(void* const* d_in, const int* in_sizes, int n_in,
                              void* d_out, int out_size, void* d_ws, size_t ws_size,
                              hipStream_t stream) {
  const float* state = (const float*)d_in[0];
  const float* gW0   = (const float*)d_in[1];
  const float* gb0   = (const float*)d_in[2];
  const float* gW1   = (const float*)d_in[3];
  const float* gb1   = (const float*)d_in[4];
  const float* fW0   = (const float*)d_in[5];
  const float* fb0   = (const float*)d_in[6];
  const float* fW1   = (const float*)d_in[7];
  const float* fb1   = (const float*)d_in[8];
  float* out = (float*)d_out;

  _Float16* W0c = (_Float16*)d_ws;                      // 65536 fp16 = 128KB
  _Float16* W1c = W0c + 65536;                          // 65536 fp16 = 128KB
  float* pooled = (float*)(W1c + 65536);                // 1024*256 f32 = 1MB

  const int Bn = in_sizes[0] / 2048;  // 1024

  prep_kernel<<<dim3(256), dim3(256), 0, stream>>>(gW0, gW1, W0c, W1c);
  pair_kernel<<<dim3(Bn), dim3(256), 0, stream>>>(state, W0c, gb0, W1c, gb1, pooled);
  fmlp_kernel<<<dim3(Bn / 4), dim3(256), 0, stream>>>(pooled, fW0, fb0, fW1, fb1, out);
}

// Round 12
// 73.947 us; speedup vs baseline: 1.0548x; 1.0548x over previous
//
#include <hip/hip_runtime.h>

typedef __attribute__((ext_vector_type(8))) _Float16 f16x8;
typedef __attribute__((ext_vector_type(4))) float f32x4;

#define HSTR 264   // fp16 per A/C row (528B): 16B-aligned, staggered banks

// ---- prep: weights -> fp16, fragment-contiguous (lane-major) into d_ws ----
// One wave-fragment (64 lanes x 16B) contiguous -> in-kernel weight loads are
// single fully-coalesced 1KB dwordx4 transactions.
__global__ __launch_bounds__(256) void prep_kernel(
    const float* __restrict__ gW0, const float* __restrict__ gW1,
    _Float16* __restrict__ W0c, _Float16* __restrict__ W1c)
{
  const int t = blockIdx.x * 256 + threadIdx.x;  // 0..65535
  {
    const int c = t >> 7, k = t & 127;           // c in [0,512), k in [0,128)
    const int dst = ((k >> 5) * 32 + (c >> 4)) * 512 +
                    (((k >> 3) & 3) * 16 + (c & 15)) * 8 + (k & 7);
    const int src = (k + ((c >= 256) ? 128 : 0)) * 256 + (c & 255);
    W0c[dst] = (_Float16)gW0[src];
  }
  {
    const int n = t >> 8, k = t & 255;           // n in [0,256), k in [0,256)
    const int dst = ((k >> 5) * 16 + (n >> 4)) * 512 +
                    (((k >> 3) & 3) * 16 + (n & 15)) * 8 + (k & 7);
    W1c[dst] = (_Float16)gW1[k * 256 + n];
  }
}

// ---- main: per-batch pair MLP + pooled sum, fp16, 8 waves, AGPR weights ----
// r10 (8 waves, remat'd weights) = 55us; r11 (4 waves, AGPR-resident) = 66us.
// This composes them: 8 waves x 32 N-cols AND AGPR-pinned W1 fragments.
// Budget/wave: 64 AGPR (bw) + ~64 arch VGPR = 128 unified -> with
// launch_bounds(512,4): 2 blocks/CU = 4 waves/SIMD interleave, zero in-loop
// VMEM. Inline-asm MFMA takes B from "a"; s_nops cover VALU<->MFMA hazards.
__global__ __launch_bounds__(512, 4) void pair_kernel(
    const float* __restrict__ state,
    const _Float16* __restrict__ W0c, const float* __restrict__ gb0,
    const _Float16* __restrict__ W1c, const float* __restrict__ gb1,
    float* __restrict__ pooled)
{
  const int b   = blockIdx.x;
  const int tid = threadIdx.x;
  const int w   = tid >> 6;   // wave 0..7
  const int l   = tid & 63;
  const int lr  = l & 15;
  const int lg  = l >> 4;

  __shared__ _Float16 A_lds[16 * HSTR];
  __shared__ _Float16 C_lds[16 * HSTR];

  const float* stb = state + (size_t)b * 2048;

  // ---------------- Phase 2: [A|C] = state[16x128] @ W0 (fp16 MFMA) ----------------
  f16x8 sfrag[4];
  #pragma unroll
  for (int kk = 0; kk < 4; ++kk) {
    const float* sp = stb + lr * 128 + kk * 32 + lg * 8;
    f32x4 s0 = *(const f32x4*)sp;
    f32x4 s1 = *(const f32x4*)(sp + 4);
    f16x8 f;
    f[0] = (_Float16)s0[0]; f[1] = (_Float16)s0[1];
    f[2] = (_Float16)s0[2]; f[3] = (_Float16)s0[3];
    f[4] = (_Float16)s1[0]; f[5] = (_Float16)s1[1];
    f[6] = (_Float16)s1[2]; f[7] = (_Float16)s1[3];
    sfrag[kk] = f;
  }

  const f32x4 z4 = {0.f, 0.f, 0.f, 0.f};
  f32x4 acc2[4];
  #pragma unroll
  for (int nt = 0; nt < 4; ++nt) acc2[nt] = z4;

  // wave w owns [A|C] cols [64w, 64w+64)
  #pragma unroll
  for (int nt = 0; nt < 4; ++nt) {
    #pragma unroll
    for (int kk = 0; kk < 4; ++kk) {
      f16x8 bf = *(const f16x8*)(W0c + (size_t)((kk * 32 + 4 * w + nt) * 512 + l * 8));
      acc2[nt] = __builtin_amdgcn_mfma_f32_16x16x32_f16(sfrag[kk], bf, acc2[nt], 0, 0, 0);
    }
  }

  // store phase-2 results as fp16 (C/D layout: col=lr, row=lg*4+r); fold gb0
  #pragma unroll
  for (int nt = 0; nt < 4; ++nt) {
    const int col = 64 * w + 16 * nt + lr;
    #pragma unroll
    for (int r = 0; r < 4; ++r) {
      const int row = lg * 4 + r;
      const float v = acc2[nt][r];
      if (col < 256) A_lds[row * HSTR + col]       = (_Float16)(v + gb0[col]);
      else           C_lds[row * HSTR + col - 256] = (_Float16)v;
    }
  }

  // W1 fragments: wave w owns N-cols [32w, 32w+32) -> 2nt x 8kk frags.
  // Pin into AGPR tuples: opaque defs, zero VGPR-class pressure, no remat.
  f16x8 bw[2][8];
  #pragma unroll
  for (int nt = 0; nt < 2; ++nt) {
    #pragma unroll
    for (int kk = 0; kk < 8; ++kk) {
      bw[nt][kk] = *(const f16x8*)(W1c + (size_t)((kk * 16 + 2 * w + nt) * 512 + l * 8));
      asm volatile("" : "+a"(bw[nt][kk]));   // park in AGPR
    }
  }

  float gb1v[2];
  #pragma unroll
  for (int nt = 0; nt < 2; ++nt) gb1v[nt] = gb1[32 * w + 16 * nt + lr];

  __syncthreads();

  // C rows -> fp16 registers: lane (lr,lg) holds C[lr][kk*32+lg*8 .. +8]
  f16x8 creg[8];
  #pragma unroll
  for (int kk = 0; kk < 8; ++kk)
    creg[kk] = *(const f16x8*)&C_lds[lr * HSTR + kk * 32 + lg * 8];

  const f16x8 zh = {(_Float16)0, (_Float16)0, (_Float16)0, (_Float16)0,
                    (_Float16)0, (_Float16)0, (_Float16)0, (_Float16)0};

  // ---------------- Phase 3: 16 i-tiles; u = relu(A_i + C_j) in fp16 ----------------
  float pp[2] = {0.f, 0.f};
  #pragma unroll 1
  for (int i = 0; i < 16; ++i) {
    f32x4 a0 = z4, a1 = z4;
    #pragma unroll
    for (int kk = 0; kk < 8; ++kk) {
      f16x8 av = *(const f16x8*)&A_lds[i * HSTR + kk * 32 + lg * 8];  // bcast read
      f16x8 u = __builtin_elementwise_max(av + creg[kk], zh);
      // s_nop covers VALU-write(u) -> MFMA-read (asm opaque to hazard recognizer)
      asm volatile("s_nop 3\n\tv_mfma_f32_16x16x32_f16 %0, %1, %2, %0"
                   : "+v"(a0) : "v"(u), "a"(bw[0][kk]));
      asm volatile("v_mfma_f32_16x16x32_f16 %0, %1, %2, %0"
                   : "+v"(a1) : "v"(u), "a"(bw[1][kk]));
    }
    // MFMA-write -> VALU-read spacing before the epilogue reads accs
    asm volatile("s_nop 7\n\ts_nop 7");

    #pragma unroll
    for (int r = 0; r < 4; ++r) {
      const int row = lg * 4 + r;       // = j
      const float v0 = fmaxf(a0[r] + gb1v[0], 0.f);
      const float v1 = fmaxf(a1[r] + gb1v[1], 0.f);
      pp[0] += (row == i) ? 0.f : v0;   // mask the (i,i) filler pair
      pp[1] += (row == i) ? 0.f : v1;
    }
  }

  // reduce the 4 lane-groups (disjoint j subsets, same col), write pooled
  #pragma unroll
  for (int nt = 0; nt < 2; ++nt) {
    float v = pp[nt];
    v += __shfl_xor(v, 16);
    v += __shfl_xor(v, 32);
    if (lg == 0) pooled[(size_t)b * 256 + 32 * w + 16 * nt + lr] = v;
  }
}

// ---- f-MLP: 256 blocks x 4 batches (all CUs busy; weights L2-resident) ----
__global__ __launch_bounds__(256) void fmlp_kernel(
    const float* __restrict__ pooled,
    const float* __restrict__ fW0, const float* __restrict__ fb0,
    const float* __restrict__ fW1, const float* __restrict__ fb1,
    float* __restrict__ out)
{
  const int tid = threadIdx.x;
  const size_t b0 = (size_t)blockIdx.x * 4;
  __shared__ float pl[4][256];
  __shared__ float h1[4][256];

  #pragma unroll
  for (int q = 0; q < 4; ++q)
    pl[q][tid] = pooled[(b0 + q) * 256 + tid];
  __syncthreads();

  float acc[4] = {0.f, 0.f, 0.f, 0.f};
  #pragma unroll 8
  for (int k = 0; k < 256; ++k) {
    const float wv = fW0[(size_t)k * 256 + tid];
    #pragma unroll
    for (int q = 0; q < 4; ++q) acc[q] = fmaf(pl[q][k], wv, acc[q]);
  }
  #pragma unroll
  for (int q = 0; q < 4; ++q) h1[q][tid] = fmaxf(acc[q] + fb0[tid], 0.f);
  __syncthreads();

  float acc2[4] = {0.f, 0.f, 0.f, 0.f};
  #pragma unroll 8
  for (int k = 0; k < 256; ++k) {
    const float wv = fW1[(size_t)k * 256 + tid];
    #pragma unroll
    for (int q = 0; q < 4; ++q) acc2[q] = fmaf(h1[q][k], wv, acc2[q]);
  }
  #pragma unroll
  for (int q = 0; q < 4; ++q)
    out[(b0 + q) * 256 + tid] = fmaxf(acc2[q] + fb1[tid], 0.f);
}

extern "C" void kernel_launch(void* const* d_in, const int* in_sizes, int n_in,
                              void* d_out, int out_size, void* d_ws, size_t ws_size,
                              hipStream_t stream) {
  const float* state = (const float*)d_in[0];
  const float* gW0   = (const float*)d_in[1];
  const float* gb0   = (const float*)d_in[2];
  const float* gW1   = (const float*)d_in[3];
  const float* gb1   = (const float*)d_in[4];
  const float* fW0   = (const float*)d_in[5];
  const float* fb0   = (const float*)d_in[6];
  const float* fW1   = (const float*)d_in[7];
  const float* fb1   = (const float*)d_in[8];
  float* out = (float*)d_out;

  _Float16* W0c = (_Float16*)d_ws;                      // 65536 fp16 = 128KB
  _Float16* W1c = W0c + 65536;                          // 65536 fp16 = 128KB
  float* pooled = (float*)(W1c + 65536);                // 1024*256 f32 = 1MB

  const int Bn = in_sizes[0] / 2048;  // 1024

  prep_kernel<<<dim3(256), dim3(256), 0, stream>>>(gW0, gW1, W0c, W1c);
  pair_kernel<<<dim3(Bn), dim3(512), 0, stream>>>(state, W0c, gb0, W1c, gb1, pooled);
  fmlp_kernel<<<dim3(Bn / 4), dim3(256), 0, stream>>>(pooled, fW0, fb0, fW1, fb1, out);
}

// Round 13
// 71.504 us; speedup vs baseline: 1.0908x; 1.0342x over previous
//
#include <hip/hip_runtime.h>

typedef __attribute__((ext_vector_type(8))) _Float16 f16x8;
typedef __attribute__((ext_vector_type(4))) float f32x4;

#define HSTR 264   // fp16 per A/C row (528B): 16B-aligned, staggered banks

// ---- prep: weights -> fp16, fragment-contiguous (lane-major) into d_ws ----
__global__ __launch_bounds__(256) void prep_kernel(
    const float* __restrict__ gW0, const float* __restrict__ gW1,
    _Float16* __restrict__ W0c, _Float16* __restrict__ W1c)
{
  const int t = blockIdx.x * 256 + threadIdx.x;  // 0..65535
  {
    const int c = t >> 7, k = t & 127;           // c in [0,512), k in [0,128)
    const int dst = ((k >> 5) * 32 + (c >> 4)) * 512 +
                    (((k >> 3) & 3) * 16 + (c & 15)) * 8 + (k & 7);
    const int src = (k + ((c >= 256) ? 128 : 0)) * 256 + (c & 255);
    W0c[dst] = (_Float16)gW0[src];
  }
  {
    const int n = t >> 8, k = t & 255;           // n in [0,256), k in [0,256)
    const int dst = ((k >> 5) * 16 + (n >> 4)) * 512 +
                    (((k >> 3) & 3) * 16 + (n & 15)) * 8 + (k & 7);
    W1c[dst] = (_Float16)gW1[k * 256 + n];
  }
}

// ---- main: producer/consumer u via LDS + AGPR-resident W1 ----
// r12 counters: u-build redundancy (8 waves x same u) = the VALU wall; MFMA
// pipe latency-occupied (16.5 cyc/MFMA) not throughput-fed. This round: per
// round g, wave w PRODUCES u-tile i=4g+(w>>1) for kk-half (w&1) -- u built
// ONCE per batch (8x less u-VALU) -- into a 32KB swizzled LDS buffer; after
// a barrier all 8 waves CONSUME all 4 tiles: pure ds_read_b128 -> 2 asm MFMA
// (B operands AGPR-pinned, r11/r12-proven no-remat). Zero VALU/VMEM in the
// MFMA loop. 64 AGPR + ~60 VGPR -> 2 blocks/CU (4 waves/SIMD).
__global__ __launch_bounds__(512, 4) void pair_kernel(
    const float* __restrict__ state,
    const _Float16* __restrict__ W0c, const float* __restrict__ gb0,
    const _Float16* __restrict__ W1c, const float* __restrict__ gb1,
    float* __restrict__ pooled)
{
  const int b   = blockIdx.x;
  const int tid = threadIdx.x;
  const int w   = tid >> 6;   // wave 0..7
  const int l   = tid & 63;
  const int lr  = l & 15;
  const int lg  = l >> 4;

  // [0, 8448) A_lds f16 [16][HSTR]; [8448, 8448+32768) ubuf (C staged there first)
  __shared__ __align__(16) char smem[8448 + 32768];
  _Float16* A_lds = (_Float16*)smem;
  char*     ubuf  = smem + 8448;
  _Float16* C_st  = (_Float16*)ubuf;   // staging overlay, dead after creg capture

  const float* stb = state + (size_t)b * 2048;

  // ---------------- Phase 2: [A|C] = state[16x128] @ W0 (fp16 MFMA) ----------------
  f16x8 sfrag[4];
  #pragma unroll
  for (int kk = 0; kk < 4; ++kk) {
    const float* sp = stb + lr * 128 + kk * 32 + lg * 8;
    f32x4 s0 = *(const f32x4*)sp;
    f32x4 s1 = *(const f32x4*)(sp + 4);
    f16x8 f;
    f[0] = (_Float16)s0[0]; f[1] = (_Float16)s0[1];
    f[2] = (_Float16)s0[2]; f[3] = (_Float16)s0[3];
    f[4] = (_Float16)s1[0]; f[5] = (_Float16)s1[1];
    f[6] = (_Float16)s1[2]; f[7] = (_Float16)s1[3];
    sfrag[kk] = f;
  }

  const f32x4 z4 = {0.f, 0.f, 0.f, 0.f};
  f32x4 acc2[4];
  #pragma unroll
  for (int nt = 0; nt < 4; ++nt) acc2[nt] = z4;

  // wave w owns [A|C] cols [64w, 64w+64)
  #pragma unroll
  for (int nt = 0; nt < 4; ++nt) {
    #pragma unroll
    for (int kk = 0; kk < 4; ++kk) {
      f16x8 bf = *(const f16x8*)(W0c + (size_t)((kk * 32 + 4 * w + nt) * 512 + l * 8));
      acc2[nt] = __builtin_amdgcn_mfma_f32_16x16x32_f16(sfrag[kk], bf, acc2[nt], 0, 0, 0);
    }
  }

  // W1 fragments for this wave's N-cols [32w,32w+32): AGPR-pinned, no remat
  f16x8 bw[2][8];
  #pragma unroll
  for (int nt = 0; nt < 2; ++nt) {
    #pragma unroll
    for (int kk = 0; kk < 8; ++kk) {
      bw[nt][kk] = *(const f16x8*)(W1c + (size_t)((kk * 16 + 2 * w + nt) * 512 + l * 8));
      asm volatile("" : "+a"(bw[nt][kk]));   // park in AGPR
    }
  }
  float gb1v[2];
  gb1v[0] = gb1[32 * w + lr];
  gb1v[1] = gb1[32 * w + 16 + lr];

  // store phase-2 results as fp16 (C/D layout: col=lr, row=lg*4+r); fold gb0
  #pragma unroll
  for (int nt = 0; nt < 4; ++nt) {
    const int col = 64 * w + 16 * nt + lr;
    #pragma unroll
    for (int r = 0; r < 4; ++r) {
      const int row = lg * 4 + r;
      const float v = acc2[nt][r];
      if (col < 256) A_lds[row * HSTR + col]       = (_Float16)(v + gb0[col]);
      else           C_st[row * HSTR + col - 256]  = (_Float16)v;
    }
  }
  __syncthreads();

  // creg: only this wave's kk-half (w&1): kk = kh..kh+3 -> 16 VGPR
  const int kh = (w & 1) * 4;
  f16x8 creg[4];
  #pragma unroll
  for (int kq = 0; kq < 4; ++kq)
    creg[kq] = *(const f16x8*)&C_st[lr * HSTR + (kh + kq) * 32 + lg * 8];
  __syncthreads();   // C_st dead; ubuf writable

  // swizzled per-lane 16B slot within a (tile,kk) 1KB block:
  // j=lr in 64B rows, k-sub=lg*16; XOR bits 4-6 with lr&7 (bijective, ~2-way banks)
  const int lrd = (lr * 64 + lg * 16) ^ ((lr & 7) << 4);

  const f16x8 zh = {(_Float16)0, (_Float16)0, (_Float16)0, (_Float16)0,
                    (_Float16)0, (_Float16)0, (_Float16)0, (_Float16)0};

  float pp0 = 0.f, pp1 = 0.f;

  #pragma unroll 1
  for (int g = 0; g < 4; ++g) {
    // ---- produce: wave w builds tile i = 4g + (w>>1), kk in [kh, kh+4) ----
    {
      const int ip = 4 * g + (w >> 1);
      char* tb = ubuf + (w >> 1) * 8192;
      #pragma unroll
      for (int kq = 0; kq < 4; ++kq) {
        const int kk = kh + kq;
        f16x8 av = *(const f16x8*)&A_lds[ip * HSTR + kk * 32 + lg * 8];  // bcast
        f16x8 u = __builtin_elementwise_max(av + creg[kq], zh);
        *(f16x8*)(tb + kk * 1024 + lrd) = u;
      }
    }
    __syncthreads();   // all 4 tiles of this round ready

    // ---- consume: all 4 tiles, pure ds_read_b128 -> MFMA (AGPR B) ----
    #pragma unroll
    for (int t = 0; t < 4; ++t) {
      const char* tb = ubuf + t * 8192;
      f32x4 a0 = z4, a1 = z4;
      #pragma unroll
      for (int kk = 0; kk < 8; ++kk) {
        f16x8 uf = *(const f16x8*)(tb + kk * 1024 + lrd);
        // s_nop 3 covers VALU-write(acc init / prior epilogue) -> MFMA hazard
        if (kk == 0)
          asm volatile("s_nop 3\n\tv_mfma_f32_16x16x32_f16 %0, %1, %2, %0"
                       : "+v"(a0) : "v"(uf), "a"(bw[0][kk]));
        else
          asm volatile("v_mfma_f32_16x16x32_f16 %0, %1, %2, %0"
                       : "+v"(a0) : "v"(uf), "a"(bw[0][kk]));
        asm volatile("v_mfma_f32_16x16x32_f16 %0, %1, %2, %0"
                     : "+v"(a1) : "v"(uf), "a"(bw[1][kk]));
      }
      asm volatile("s_nop 7\n\ts_nop 7");   // MFMA-write -> VALU-read spacing

      const int i = 4 * g + t;
      #pragma unroll
      for (int r = 0; r < 4; ++r) {
        const int row = lg * 4 + r;       // = j
        const float v0 = fmaxf(a0[r] + gb1v[0], 0.f);
        const float v1 = fmaxf(a1[r] + gb1v[1], 0.f);
        pp0 += (row == i) ? 0.f : v0;     // mask the (i,i) filler pair
        pp1 += (row == i) ? 0.f : v1;
      }
    }
    __syncthreads();   // tiles consumed; next round may overwrite ubuf
  }

  // reduce the 4 lane-groups (disjoint j subsets, same col), write pooled
  {
    float v = pp0;
    v += __shfl_xor(v, 16);
    v += __shfl_xor(v, 32);
    if (lg == 0) pooled[(size_t)b * 256 + 32 * w + lr] = v;
  }
  {
    float v = pp1;
    v += __shfl_xor(v, 16);
    v += __shfl_xor(v, 32);
    if (lg == 0) pooled[(size_t)b * 256 + 32 * w + 16 + lr] = v;
  }
}

// ---- f-MLP: 256 blocks x 4 batches (all CUs busy; weights L2-resident) ----
__global__ __launch_bounds__(256) void fmlp_kernel(
    const float* __restrict__ pooled,
    const float* __restrict__ fW0, const float* __restrict__ fb0,
    const float* __restrict__ fW1, const float* __restrict__ fb1,
    float* __restrict__ out)
{
  const int tid = threadIdx.x;
  const size_t b0 = (size_t)blockIdx.x * 4;
  __shared__ float pl[4][256];
  __shared__ float h1[4][256];

  #pragma unroll
  for (int q = 0; q < 4; ++q)
    pl[q][tid] = pooled[(b0 + q) * 256 + tid];
  __syncthreads();

  float acc[4] = {0.f, 0.f, 0.f, 0.f};
  #pragma unroll 8
  for (int k = 0; k < 256; ++k) {
    const float wv = fW0[(size_t)k * 256 + tid];
    #pragma unroll
    for (int q = 0; q < 4; ++q) acc[q] = fmaf(pl[q][k], wv, acc[q]);
  }
  #pragma unroll
  for (int q = 0; q < 4; ++q) h1[q][tid] = fmaxf(acc[q] + fb0[tid], 0.f);
  __syncthreads();

  float acc2[4] = {0.f, 0.f, 0.f, 0.f};
  #pragma unroll 8
  for (int k = 0; k < 256; ++k) {
    const float wv = fW1[(size_t)k * 256 + tid];
    #pragma unroll
    for (int q = 0; q < 4; ++q) acc2[q] = fmaf(h1[q][k], wv, acc2[q]);
  }
  #pragma unroll
  for (int q = 0; q < 4; ++q)
    out[(b0 + q) * 256 + tid] = fmaxf(acc2[q] + fb1[tid], 0.f);
}

extern "C" void kernel_launch(void* const* d_in, const int* in_sizes, int n_in,
                              void* d_out, int out_size, void* d_ws, size_t ws_size,
                              hipStream_t stream) {
  const float* state = (const float*)d_in[0];
  const float* gW0   = (const float*)d_in[1];
  const float* gb0   = (const float*)d_in[2];
  const float* gW1   = (const float*)d_in[3];
  const float* gb1   = (const float*)d_in[4];
  const float* fW0   = (const float*)d_in[5];
  const float* fb0   = (const float*)d_in[6];
  const float* fW1   = (const float*)d_in[7];
  const float* fb1   = (const float*)d_in[8];
  float* out = (float*)d_out;

  _Float16* W0c = (_Float16*)d_ws;                      // 65536 fp16 = 128KB
  _Float16* W1c = W0c + 65536;                          // 65536 fp16 = 128KB
  float* pooled = (float*)(W1c + 65536);                // 1024*256 f32 = 1MB

  const int Bn = in_sizes[0] / 2048;  // 1024

  prep_kernel<<<dim3(256), dim3(256), 0, stream>>>(gW0, gW1, W0c, W1c);
  pair_kernel<<<dim3(Bn), dim3(512), 0, stream>>>(state, W0c, gb0, W1c, gb1, pooled);
  fmlp_kernel<<<dim3(Bn / 4), dim3(256), 0, stream>>>(pooled, fW0, fb0, fW1, fb1, out);
}